// Round 5
// baseline (128.308 us; speedup 1.0000x reference)
//
#include <hip/hip_runtime.h>

typedef __bf16 bf16x8 __attribute__((ext_vector_type(8)));
typedef float f32x4 __attribute__((ext_vector_type(4)));
typedef unsigned int u32;
typedef unsigned short u16;

#define DEV static __device__ __forceinline__

DEV u16 f2bf(float f){
  __bf16 h = (__bf16)f;
  u16 u; __builtin_memcpy(&u, &h, 2); return u;
}
DEV float bf2f(u16 u){
  u32 x = ((u32)u) << 16;
  float f; __builtin_memcpy(&f, &x, 4); return f;
}
DEV u32 pack2bf(float lo, float hi){
  return (u32)f2bf(lo) | ((u32)f2bf(hi) << 16);
}
DEV void gll16(void* lds, const void* g){
  __builtin_amdgcn_global_load_lds((const __attribute__((address_space(1))) void*)g,
                                   (__attribute__((address_space(3))) void*)lds, 16, 0, 0);
}

// ---------------- fused cast f32 -> bf16 (x, w_qkv, w_o in one launch) ----------------
__global__ __launch_bounds__(256) void cast3_f32_bf16(
    const float* __restrict__ x, const float* __restrict__ wqkv,
    const float* __restrict__ wo, u16* __restrict__ xb,
    u16* __restrict__ wqkvb, u16* __restrict__ wob)
{
  const int NX = 1048576, NW = 786432, NO = 262144;   // float4 counts
  int i = blockIdx.x * blockDim.x + threadIdx.x;
  int stride = gridDim.x * blockDim.x;
  for (; i < NX + NW + NO; i += stride){
    const float4* s; u16* d; int j;
    if (i < NX){ s = (const float4*)x; d = xb; j = i; }
    else if (i < NX + NW){ s = (const float4*)wqkv; d = wqkvb; j = i - NX; }
    else { s = (const float4*)wo; d = wob; j = i - NX - NW; }
    float4 v = s[j];
    ushort4 o;
    o.x = f2bf(v.x); o.y = f2bf(v.y); o.z = f2bf(v.z); o.w = f2bf(v.w);
    ((ushort4*)d)[j] = o;
  }
}

// ------- GEMM: Y[M,N] = A[M,K] * B[N,K]^T, K=1024; tile BM x BN, dbuf, unroll-2 -------
// verified 2-phase template (round-0 structure); BM/BN are geometry-only parameters.
// 4 waves in 2x2; wave tile (BM/2)x(BN/2); acc (BM/32)x(BN/32) of 16x16 frags.
template<int BM, int BN, int MW>
__global__ __launch_bounds__(256, MW) void gemm_dbuf(
    const u16* __restrict__ A, const u16* __restrict__ B,
    u16* __restrict__ qbuf, u16* __restrict__ kbuf, u16* __restrict__ vbuf,
    float* __restrict__ fout, int mode)
{
  __shared__ __align__(16) u16 As[2][BM*32];    // [buf][row BM][col 32], swizzled granules
  __shared__ __align__(16) u16 Bs[2][BN*32];    // [buf][row BN][col 32]
  const int tid = threadIdx.x;
  const int ln  = tid & 63;
  const int w   = tid >> 6;
  const int wr = w >> 1, wc = w & 1;            // wave-tile (BM/2) x (BN/2)
  const int l15 = ln & 15, lg = ln >> 4;
  const int tM = blockIdx.y * BM, tN = blockIdx.x * BN;
  const int K = 1024;

  f32x4 acc[BM/32][BN/32] = {};

  const int grow = tid >> 2;                    // 0..63: row within a 64-row chunk
  const int gswz = ((tid & 3) ^ (grow & 3)) * 8;
  const u16* ap = A + (size_t)(tM + grow) * K + gswz;
  const u16* bp = B + (size_t)(tN + grow) * K + gswz;

  // each 64-row chunk cc: rows cc*64 + grow; (cc*64+grow)&3 == grow&3, swizzle invariant
  #define GSTAGE(buf_, k0_) do { \
    _Pragma("unroll") \
    for (int cc = 0; cc < BM/64; cc++) \
      gll16(&As[buf_][cc*2048 + w*512], ap + (size_t)cc*64*K + (k0_)); \
    _Pragma("unroll") \
    for (int cc = 0; cc < BN/64; cc++) \
      gll16(&Bs[buf_][cc*2048 + w*512], bp + (size_t)cc*64*K + (k0_)); \
  } while(0)

  #define WAITPREV() do { \
    if constexpr (BM/64 + BN/64 == 4) asm volatile("s_waitcnt vmcnt(4)" ::: "memory"); \
    else                              asm volatile("s_waitcnt vmcnt(3)" ::: "memory"); \
  } while(0)

  const int rg = (lg ^ (l15 & 3)) * 8;          // swizzled read-granule offset (u16)

  #define GCOMP(BUF) do { \
    bf16x8 af[BM/32], bfr[BN/32]; \
    _Pragma("unroll") \
    for (int m = 0; m < BM/32; m++) \
      af[m] = *(const bf16x8*)(&As[BUF][(wr*(BM/2) + m*16 + l15)*32 + rg]); \
    _Pragma("unroll") \
    for (int n = 0; n < BN/32; n++) \
      bfr[n] = *(const bf16x8*)(&Bs[BUF][(wc*(BN/2) + n*16 + l15)*32 + rg]); \
    _Pragma("unroll") \
    for (int m = 0; m < BM/32; m++) \
      _Pragma("unroll") \
      for (int n = 0; n < BN/32; n++) \
        acc[m][n] = __builtin_amdgcn_mfma_f32_16x16x32_bf16(af[m], bfr[n], acc[m][n], 0, 0, 0); \
  } while(0)

  GSTAGE(0, 0);
  #pragma unroll 1
  for (int k0 = 0; k0 < K; k0 += 64){
    // half A: compute buf0 (tile k0), stage tile k0+32 into buf1
    if (k0 + 32 < K){
      GSTAGE(1, k0 + 32);
      WAITPREV();
    } else {
      asm volatile("s_waitcnt vmcnt(0)" ::: "memory");
    }
    __builtin_amdgcn_s_barrier();
    __builtin_amdgcn_sched_barrier(0);
    GCOMP(0);
    __builtin_amdgcn_s_barrier();
    // half B: compute buf1 (tile k0+32), stage tile k0+64 into buf0
    if (k0 + 64 < K){
      GSTAGE(0, k0 + 64);
      WAITPREV();
    } else {
      asm volatile("s_waitcnt vmcnt(0)" ::: "memory");
    }
    __builtin_amdgcn_s_barrier();
    __builtin_amdgcn_sched_barrier(0);
    GCOMP(1);
    __builtin_amdgcn_s_barrier();
  }
  #undef GSTAGE
  #undef GCOMP
  #undef WAITPREV

  #pragma unroll
  for (int m = 0; m < BM/32; m++){
    #pragma unroll
    for (int n = 0; n < BN/32; n++){
      #pragma unroll
      for (int r = 0; r < 4; r++){
        int row = tM + wr*(BM/2) + m*16 + lg*4 + r;
        int col = tN + wc*(BN/2) + n*16 + l15;
        float v = acc[m][n][r];
        if (mode == 0){
          int t = col >> 10, rem = col & 1023;
          int h = rem >> 6, d = rem & 63;
          int b = row >> 11, s = row & 2047;
          size_t idx = ((size_t)(b*16 + h)*2048 + s)*64 + d;
          if (t == 0)      qbuf[idx] = f2bf(v * 0.125f);
          else if (t == 1) kbuf[idx] = f2bf(v);
          else             vbuf[idx] = f2bf(v);
        } else {
          fout[(size_t)row * 1024 + col] = v;
        }
      }
    }
  }
}

// ---------------- V transpose: [bh][2048][64] -> [bh][64][2048] ----------------
__global__ __launch_bounds__(256) void transpose_v(const u16* __restrict__ v,
                                                   u16* __restrict__ vt){
  __shared__ u16 T[64*66];
  const int bh = blockIdx.y;
  const int s0 = blockIdx.x * 64;
  const int tid = threadIdx.x;
  #pragma unroll
  for (int i = 0; i < 2; i++){
    int g = i*256 + tid;
    int s = g >> 3, c = g & 7;
    bf16x8 val = *(const bf16x8*)(v + ((size_t)bh*2048 + s0 + s)*64 + c*8);
    #pragma unroll
    for (int jj = 0; jj < 8; jj++)
      T[(c*8 + jj)*66 + s] = ((u16*)&val)[jj];
  }
  __syncthreads();
  #pragma unroll
  for (int i = 0; i < 2; i++){
    int og = i*256 + tid;
    int d = og >> 3, sc = og & 7;
    u32 vals[4];
    #pragma unroll
    for (int q = 0; q < 4; q++)
      vals[q] = *(const u32*)(&T[d*66 + sc*8 + q*2]);
    *(int4*)(vt + ((size_t)bh*64 + d)*2048 + s0 + sc*8) = *(const int4*)vals;
  }
}

// ---------------- causal flash attention, kv-split, queue-fed, unroll-2 ----------------
__global__ __launch_bounds__(128) void attn_fwd(
    const u16* __restrict__ qb, const u16* __restrict__ kb,
    const u16* __restrict__ vt, u16* __restrict__ ob,
    u16* __restrict__ pO, float* __restrict__ pS)
{
  __shared__ __align__(16) u16 Ks[2][2048];   // [kv 32][d 64], XOR-swizzled granules
  __shared__ __align__(16) u16 Vs[2][2048];   // [d 64][kv 32], XOR-swizzled granules
  const int tid = threadIdx.x;
  const int ln = tid & 63;
  const int w = tid >> 6;               // 0..1
  const int l15 = ln & 15, lg = ln >> 4;
  const float L2E = 1.4426950408889634f;

  // item decode: B -> {xcd, bh_local, j}; j in 0..95 ordered longest-first
  const int B = blockIdx.x;             // 0..3071
  const int xcd = B & 7;
  const int rest = B >> 3;              // 0..383
  const int bhl = rest & 3;
  const int j = rest >> 2;              // 0..95
  const int bh = xcd * 4 + bhl;
  int ti, t0, t1, split, c;
  if (j < 32){ ti = 32 + j; t0 = 0; t1 = 32; split = 1; c = 0; }
  else {
    int k = j - 32; int v = 32 - (k >> 1);      // v: 32..1
    if ((k & 1) == 0){ ti = v - 1;  t0 = 0;  t1 = ti + 1; split = 0; c = 0; }
    else             { ti = 31 + v; t0 = 32; t1 = ti + 1; split = 1; c = 1; }
  }
  const int nt = ti + 1;
  const int wq0 = ti * 32 + w * 16;
  const int b_out = bh >> 4, h_out = bh & 15;

  const int kg = (ln & 7) ^ (ln >> 3);
  const int vg = (ln & 3) ^ ((ln >> 3) & 3);
  const u16* kp0 = kb + ((size_t)bh*2048 + (ln >> 3))*64 + kg*8;
  const u16* vp0 = vt + ((size_t)bh*64  + (ln >> 2))*2048 + vg*8;

  #define STAGE(bf_, kv0_) do { \
    gll16(&Ks[bf_][(w*2 + 0)*512], kp0 + (size_t)((kv0_) + (w*2+0)*8)*64); \
    gll16(&Ks[bf_][(w*2 + 1)*512], kp0 + (size_t)((kv0_) + (w*2+1)*8)*64); \
    gll16(&Vs[bf_][(w*2 + 0)*512], vp0 + (size_t)((w*2+0)*16)*2048 + (kv0_)); \
    gll16(&Vs[bf_][(w*2 + 1)*512], vp0 + (size_t)((w*2+1)*16)*2048 + (kv0_)); \
  } while(0)

  bf16x8 qf[2];
  #pragma unroll
  for (int ks = 0; ks < 2; ks++)
    qf[ks] = *(const bf16x8*)(qb + ((size_t)bh*2048 + wq0 + l15)*64 + ks*32 + lg*8);

  f32x4 ot[4] = {};
  float m_run = -3e38f;
  float l_loc = 0.f;

  // compute one kv tile from static buffer BUF (addresses loop-invariant)
  #define BODY(BUF) do { \
    const int kv0 = t * 32; \
    f32x4 st[2] = {}; \
    __builtin_amdgcn_s_setprio(1); \
    _Pragma("unroll") \
    for (int ks = 0; ks < 2; ks++){ \
      bf16x8 kf[2]; \
      _Pragma("unroll") \
      for (int an = 0; an < 2; an++) \
        kf[an] = *(const bf16x8*)(&Ks[BUF][(an*16 + l15)*64 + (((ks*4 + lg) ^ (l15 & 7)) * 8)]); \
      _Pragma("unroll") \
      for (int an = 0; an < 2; an++) \
        st[an] = __builtin_amdgcn_mfma_f32_16x16x32_bf16(kf[an], qf[ks], st[an], 0, 0, 0); \
    } \
    __builtin_amdgcn_s_setprio(0); \
    if (t == nt - 1){ \
      _Pragma("unroll") \
      for (int an = 0; an < 2; an++) \
        _Pragma("unroll") \
        for (int rr = 0; rr < 4; rr++){ \
          int kv = kv0 + an*16 + lg*4 + rr; \
          int q  = wq0 + l15; \
          if (kv > q) st[an][rr] = -3e38f; \
        } \
    } \
    float mx0 = fmaxf(fmaxf(st[0][0], st[0][1]), fmaxf(st[0][2], st[0][3])); \
    float mx1 = fmaxf(fmaxf(st[1][0], st[1][1]), fmaxf(st[1][2], st[1][3])); \
    float lmax = fmaxf(mx0, mx1); \
    float m0 = m_run; \
    if (__any(lmax > m0 + 8.f)){ \
      float tmax = fmaxf(lmax, __shfl_xor(lmax, 16)); \
      tmax = fmaxf(tmax, __shfl_xor(tmax, 32)); \
      float mnew = fmaxf(m0, tmax); \
      float alpha = __builtin_amdgcn_exp2f((m0 - mnew) * L2E); \
      m_run = mnew; \
      l_loc *= alpha; \
      _Pragma("unroll") \
      for (int dm = 0; dm < 4; dm++){ \
        ot[dm][0] *= alpha; ot[dm][1] *= alpha; \
        ot[dm][2] *= alpha; ot[dm][3] *= alpha; \
      } \
      m0 = mnew; \
    } \
    u32 pk01[2], pk23[2]; \
    float psum[2]; \
    _Pragma("unroll") \
    for (int an = 0; an < 2; an++){ \
      float e0 = __builtin_amdgcn_exp2f((st[an][0] - m0) * L2E); \
      float e1 = __builtin_amdgcn_exp2f((st[an][1] - m0) * L2E); \
      float e2 = __builtin_amdgcn_exp2f((st[an][2] - m0) * L2E); \
      float e3 = __builtin_amdgcn_exp2f((st[an][3] - m0) * L2E); \
      psum[an] = (e0 + e1) + (e2 + e3); \
      pk01[an] = pack2bf(e0, e1); \
      pk23[an] = pack2bf(e2, e3); \
    } \
    l_loc += psum[0] + psum[1]; \
    const int s0l = l15 | ((lg & 1) << 5); \
    const int s2l = s0l | 16; \
    const bool hi = (lg >> 1) & 1; \
    bf16x8 vfr[4]; \
    _Pragma("unroll") \
    for (int dm = 0; dm < 4; dm++) \
      vfr[dm] = *(const bf16x8*)(&Vs[BUF][(dm*16 + l15)*32 + ((lg ^ ((l15 >> 1) & 3)) * 8)]); \
    u32 a0 = __shfl(pk01[0], s0l), b0 = __shfl(pk01[1], s0l); \
    u32 a1 = __shfl(pk23[0], s0l), b1 = __shfl(pk23[1], s0l); \
    u32 a2 = __shfl(pk01[0], s2l), b2 = __shfl(pk01[1], s2l); \
    u32 a3 = __shfl(pk23[0], s2l), b3 = __shfl(pk23[1], s2l); \
    union { u32 u[4]; bf16x8 v; } pf; \
    pf.u[0] = hi ? b0 : a0; \
    pf.u[1] = hi ? b1 : a1; \
    pf.u[2] = hi ? b2 : a2; \
    pf.u[3] = hi ? b3 : a3; \
    __builtin_amdgcn_s_setprio(1); \
    _Pragma("unroll") \
    for (int dm = 0; dm < 4; dm++) \
      ot[dm] = __builtin_amdgcn_mfma_f32_16x16x32_bf16(vfr[dm], pf.v, ot[dm], 0, 0, 0); \
    __builtin_amdgcn_s_setprio(0); \
  } while(0)

  STAGE(0, t0 * 32);
  int t = t0;
  #pragma unroll 1
  while (t < t1){
    // ---- half A: compute buf0 (tile t), stage t+1 into buf1 ----
    if (t + 1 < t1){
      STAGE(1, (t + 1) * 32);
      asm volatile("s_waitcnt vmcnt(4)" ::: "memory");
    } else {
      asm volatile("s_waitcnt vmcnt(0)" ::: "memory");
    }
    __builtin_amdgcn_s_barrier();
    __builtin_amdgcn_sched_barrier(0);
    BODY(0);
    __builtin_amdgcn_s_barrier();
    t++;
    if (t >= t1) break;
    // ---- half B: compute buf1 (tile t), stage t+1 into buf0 ----
    if (t + 1 < t1){
      STAGE(0, (t + 1) * 32);
      asm volatile("s_waitcnt vmcnt(4)" ::: "memory");
    } else {
      asm volatile("s_waitcnt vmcnt(0)" ::: "memory");
    }
    __builtin_amdgcn_s_barrier();
    __builtin_amdgcn_sched_barrier(0);
    BODY(1);
    __builtin_amdgcn_s_barrier();
    t++;
  }
  #undef STAGE
  #undef BODY

  float lsum = l_loc + __shfl_xor(l_loc, 16);
  lsum += __shfl_xor(lsum, 32);
  if (!split){
    float inv = 1.0f / lsum;
    int q = wq0 + l15;
    u16* obase = ob + (((size_t)b_out*2048 + q)*16 + h_out)*64 + lg*4;
    #pragma unroll
    for (int dm = 0; dm < 4; dm++){
      ushort4 pk;
      pk.x = f2bf(ot[dm][0] * inv);
      pk.y = f2bf(ot[dm][1] * inv);
      pk.z = f2bf(ot[dm][2] * inv);
      pk.w = f2bf(ot[dm][3] * inv);
      *(ushort4*)(obase + dm*16) = pk;
    }
  } else {
    const int sidx = (bh*32 + (ti - 32))*2 + c;
    const int qloc = w*16 + l15;
    u16* pbase = pO + (size_t)sidx*2048 + qloc*64 + lg*4;
    #pragma unroll
    for (int dm = 0; dm < 4; dm++){
      ushort4 pk;
      pk.x = f2bf(ot[dm][0]);
      pk.y = f2bf(ot[dm][1]);
      pk.z = f2bf(ot[dm][2]);
      pk.w = f2bf(ot[dm][3]);
      *(ushort4*)(pbase + dm*16) = pk;
    }
    if (lg == 0){
      pS[sidx*64 + qloc*2 + 0] = m_run;
      pS[sidx*64 + qloc*2 + 1] = lsum;
    }
  }
}

// ---------------- combine the two kv-chunks of tiles 32..63 ----------------
__global__ __launch_bounds__(128) void attn_combine(
    const u16* __restrict__ pO, const float* __restrict__ pS,
    u16* __restrict__ ob)
{
  const float L2E = 1.4426950408889634f;
  const int p = blockIdx.x;             // 0..1023
  const int bh = p >> 5;
  const int ti = 32 + (p & 31);
  const int s0 = (bh*32 + (ti - 32))*2;
  const int tid = threadIdx.x;
  const int row = tid >> 2, seg = tid & 3;

  float m0 = pS[s0*64 + row*2],     l0 = pS[s0*64 + row*2 + 1];
  float m1 = pS[(s0+1)*64 + row*2], l1 = pS[(s0+1)*64 + row*2 + 1];
  float m = fmaxf(m0, m1);
  float f0 = __builtin_amdgcn_exp2f((m0 - m) * L2E);
  float f1 = __builtin_amdgcn_exp2f((m1 - m) * L2E);
  float inv = 1.0f / (l0*f0 + l1*f1);
  f0 *= inv; f1 *= inv;

  union { int4 v[2]; u16 u[16]; } o0, o1, od;
  const u16* p0 = pO + (size_t)s0*2048 + row*64 + seg*16;
  const u16* p1 = pO + (size_t)(s0+1)*2048 + row*64 + seg*16;
  o0.v[0] = ((const int4*)p0)[0]; o0.v[1] = ((const int4*)p0)[1];
  o1.v[0] = ((const int4*)p1)[0]; o1.v[1] = ((const int4*)p1)[1];
  #pragma unroll
  for (int i = 0; i < 16; i++)
    od.u[i] = f2bf(bf2f(o0.u[i])*f0 + bf2f(o1.u[i])*f1);

  const int b = bh >> 4, h = bh & 15;
  const int q = ti*32 + row;
  u16* dst = ob + (((size_t)b*2048 + q)*16 + h)*64 + seg*16;
  ((int4*)dst)[0] = od.v[0];
  ((int4*)dst)[1] = od.v[1];
}

extern "C" void kernel_launch(void* const* d_in, const int* in_sizes, int n_in,
                              void* d_out, int out_size, void* d_ws, size_t ws_size,
                              hipStream_t stream)
{
  (void)in_sizes; (void)n_in; (void)out_size; (void)ws_size;
  const float* x    = (const float*)d_in[0];
  const float* wqkv = (const float*)d_in[2];
  const float* wo   = (const float*)d_in[3];
  float* out = (float*)d_out;

  char* ws = (char*)d_ws;
  u16* xb    = (u16*)(ws);
  u16* wqkvb = (u16*)(ws + ((size_t)8  << 20));
  u16* wob   = (u16*)(ws + ((size_t)14 << 20));
  u16* qbuf  = (u16*)(ws + ((size_t)16 << 20));
  u16* kbuf  = (u16*)(ws + ((size_t)24 << 20));
  u16* vbuf  = (u16*)(ws + ((size_t)32 << 20));
  u16* vtbuf = (u16*)(ws + ((size_t)40 << 20));
  u16* obuf  = (u16*)(ws + ((size_t)48 << 20));
  // partial buffers reuse xb/wqkvb (dead after gemm1 completes, stream-ordered)
  u16*   pO = xb;                         // 2048 slots x 4KB = 8MB
  float* pS = (float*)wqkvb;              // 2048 x 256B = 512KB

  cast3_f32_bf16<<<2048, 256, 0, stream>>>(x, wqkv, wo, xb, wqkvb, wob);
  gemm_dbuf<128,128,3><<<dim3(24, 32), 256, 0, stream>>>(xb, wqkvb, qbuf, kbuf, vbuf, nullptr, 0);
  transpose_v<<<dim3(32, 32), 256, 0, stream>>>(vbuf, vtbuf);
  attn_fwd<<<3072, 128, 0, stream>>>(qbuf, kbuf, vtbuf, obuf, pO, pS);
  attn_combine<<<1024, 128, 0, stream>>>(pO, pS, obuf);
  gemm_dbuf<128,128,3><<<dim3(8, 32), 256, 0, stream>>>(obuf, wob, nullptr, nullptr, nullptr, out, 1);
}

// Round 6
// 117.773 us; speedup vs baseline: 1.0894x; 1.0894x over previous
//
#include <hip/hip_runtime.h>

typedef __bf16 bf16x8 __attribute__((ext_vector_type(8)));
typedef float f32x4 __attribute__((ext_vector_type(4)));
typedef unsigned int u32;
typedef unsigned short u16;

#define DEV static __device__ __forceinline__

DEV u16 f2bf(float f){
  __bf16 h = (__bf16)f;
  u16 u; __builtin_memcpy(&u, &h, 2); return u;
}
DEV float bf2f(u16 u){
  u32 x = ((u32)u) << 16;
  float f; __builtin_memcpy(&f, &x, 4); return f;
}
DEV u32 pack2bf(float lo, float hi){
  return (u32)f2bf(lo) | ((u32)f2bf(hi) << 16);
}
DEV void gll16(void* lds, const void* g){
  __builtin_amdgcn_global_load_lds((const __attribute__((address_space(1))) void*)g,
                                   (__attribute__((address_space(3))) void*)lds, 16, 0, 0);
}

// ---------------- fused cast f32 -> bf16 (x, w_qkv, w_o in one launch) ----------------
__global__ __launch_bounds__(256) void cast3_f32_bf16(
    const float* __restrict__ x, const float* __restrict__ wqkv,
    const float* __restrict__ wo, u16* __restrict__ xb,
    u16* __restrict__ wqkvb, u16* __restrict__ wob)
{
  const int NX = 1048576, NW = 786432, NO = 262144;   // float4 counts
  int i = blockIdx.x * blockDim.x + threadIdx.x;
  int stride = gridDim.x * blockDim.x;
  for (; i < NX + NW + NO; i += stride){
    const float4* s; u16* d; int j;
    if (i < NX){ s = (const float4*)x; d = xb; j = i; }
    else if (i < NX + NW){ s = (const float4*)wqkv; d = wqkvb; j = i - NX; }
    else { s = (const float4*)wo; d = wob; j = i - NX - NW; }
    float4 v = s[j];
    ushort4 o;
    o.x = f2bf(v.x); o.y = f2bf(v.y); o.z = f2bf(v.z); o.w = f2bf(v.w);
    ((ushort4*)d)[j] = o;
  }
}

// ------- GEMM: Y[M,N] = A[M,K] * B[N,K]^T, K=1024; tile BM x BN, dbuf, unroll-2 -------
// verified 2-phase template (round-0 structure); BM/BN are geometry-only parameters.
// 4 waves in 2x2; wave tile (BM/2)x(BN/2); acc (BM/32)x(BN/32) of 16x16 frags.
// mode 0: QKV split-write; V third written DIRECTLY TRANSPOSED to [bh][d][s] (vbuf = vt).
template<int BM, int BN, int MW>
__global__ __launch_bounds__(256, MW) void gemm_dbuf(
    const u16* __restrict__ A, const u16* __restrict__ B,
    u16* __restrict__ qbuf, u16* __restrict__ kbuf, u16* __restrict__ vbuf,
    float* __restrict__ fout, int mode)
{
  __shared__ __align__(16) u16 As[2][BM*32];    // [buf][row BM][col 32], swizzled granules
  __shared__ __align__(16) u16 Bs[2][BN*32];    // [buf][row BN][col 32]
  const int tid = threadIdx.x;
  const int ln  = tid & 63;
  const int w   = tid >> 6;
  const int wr = w >> 1, wc = w & 1;            // wave-tile (BM/2) x (BN/2)
  const int l15 = ln & 15, lg = ln >> 4;
  const int tM = blockIdx.y * BM, tN = blockIdx.x * BN;
  const int K = 1024;

  f32x4 acc[BM/32][BN/32] = {};

  const int grow = tid >> 2;                    // 0..63: row within a 64-row chunk
  const int gswz = ((tid & 3) ^ (grow & 3)) * 8;
  const u16* ap = A + (size_t)(tM + grow) * K + gswz;
  const u16* bp = B + (size_t)(tN + grow) * K + gswz;

  // each 64-row chunk cc: rows cc*64 + grow; (cc*64+grow)&3 == grow&3, swizzle invariant
  #define GSTAGE(buf_, k0_) do { \
    _Pragma("unroll") \
    for (int cc = 0; cc < BM/64; cc++) \
      gll16(&As[buf_][cc*2048 + w*512], ap + (size_t)cc*64*K + (k0_)); \
    _Pragma("unroll") \
    for (int cc = 0; cc < BN/64; cc++) \
      gll16(&Bs[buf_][cc*2048 + w*512], bp + (size_t)cc*64*K + (k0_)); \
  } while(0)

  #define WAITPREV() do { \
    if constexpr (BM/64 + BN/64 == 4) asm volatile("s_waitcnt vmcnt(4)" ::: "memory"); \
    else                              asm volatile("s_waitcnt vmcnt(3)" ::: "memory"); \
  } while(0)

  const int rg = (lg ^ (l15 & 3)) * 8;          // swizzled read-granule offset (u16)

  #define GCOMP(BUF) do { \
    bf16x8 af[BM/32], bfr[BN/32]; \
    _Pragma("unroll") \
    for (int m = 0; m < BM/32; m++) \
      af[m] = *(const bf16x8*)(&As[BUF][(wr*(BM/2) + m*16 + l15)*32 + rg]); \
    _Pragma("unroll") \
    for (int n = 0; n < BN/32; n++) \
      bfr[n] = *(const bf16x8*)(&Bs[BUF][(wc*(BN/2) + n*16 + l15)*32 + rg]); \
    _Pragma("unroll") \
    for (int m = 0; m < BM/32; m++) \
      _Pragma("unroll") \
      for (int n = 0; n < BN/32; n++) \
        acc[m][n] = __builtin_amdgcn_mfma_f32_16x16x32_bf16(af[m], bfr[n], acc[m][n], 0, 0, 0); \
  } while(0)

  GSTAGE(0, 0);
  #pragma unroll 1
  for (int k0 = 0; k0 < K; k0 += 64){
    // half A: compute buf0 (tile k0), stage tile k0+32 into buf1
    if (k0 + 32 < K){
      GSTAGE(1, k0 + 32);
      WAITPREV();
    } else {
      asm volatile("s_waitcnt vmcnt(0)" ::: "memory");
    }
    __builtin_amdgcn_s_barrier();
    __builtin_amdgcn_sched_barrier(0);
    GCOMP(0);
    __builtin_amdgcn_s_barrier();
    // half B: compute buf1 (tile k0+32), stage tile k0+64 into buf0
    if (k0 + 64 < K){
      GSTAGE(0, k0 + 64);
      WAITPREV();
    } else {
      asm volatile("s_waitcnt vmcnt(0)" ::: "memory");
    }
    __builtin_amdgcn_s_barrier();
    __builtin_amdgcn_sched_barrier(0);
    GCOMP(1);
    __builtin_amdgcn_s_barrier();
  }
  #undef GSTAGE
  #undef GCOMP
  #undef WAITPREV

  #pragma unroll
  for (int m = 0; m < BM/32; m++){
    #pragma unroll
    for (int n = 0; n < BN/32; n++){
      const int col = tN + wc*(BN/2) + n*16 + l15;
      const int rowb = tM + wr*(BM/2) + m*16 + lg*4;   // multiple of 4
      if (mode == 0){
        const int t = col >> 10, rem = col & 1023;
        const int h = rem >> 6, d = rem & 63;
        if (t == 2){
          // direct transposed write: vt[(b*16+h)*64 + d][s], 4 consecutive s in one store
          const int b = rowb >> 11, s = rowb & 2047;
          ushort4 pk;
          pk.x = f2bf(acc[m][n][0]);
          pk.y = f2bf(acc[m][n][1]);
          pk.z = f2bf(acc[m][n][2]);
          pk.w = f2bf(acc[m][n][3]);
          *(ushort4*)(vbuf + ((size_t)(b*16 + h)*64 + d)*2048 + s) = pk;
        } else {
          #pragma unroll
          for (int r = 0; r < 4; r++){
            int row = rowb + r;
            int b = row >> 11, s = row & 2047;
            size_t idx = ((size_t)(b*16 + h)*2048 + s)*64 + d;
            if (t == 0) qbuf[idx] = f2bf(acc[m][n][r] * 0.125f);
            else        kbuf[idx] = f2bf(acc[m][n][r]);
          }
        }
      } else {
        #pragma unroll
        for (int r = 0; r < 4; r++)
          fout[(size_t)(rowb + r) * 1024 + col] = acc[m][n][r];
      }
    }
  }
}

// ---------------- causal flash attention, kv-split, queue-fed, unroll-2 ----------------
__global__ __launch_bounds__(128) void attn_fwd(
    const u16* __restrict__ qb, const u16* __restrict__ kb,
    const u16* __restrict__ vt, u16* __restrict__ ob,
    u16* __restrict__ pO, float* __restrict__ pS)
{
  __shared__ __align__(16) u16 Ks[2][2048];   // [kv 32][d 64], XOR-swizzled granules
  __shared__ __align__(16) u16 Vs[2][2048];   // [d 64][kv 32], XOR-swizzled granules
  const int tid = threadIdx.x;
  const int ln = tid & 63;
  const int w = tid >> 6;               // 0..1
  const int l15 = ln & 15, lg = ln >> 4;
  const float L2E = 1.4426950408889634f;

  // item decode: B -> {xcd, bh_local, j}; j in 0..95 ordered longest-first
  const int B = blockIdx.x;             // 0..3071
  const int xcd = B & 7;
  const int rest = B >> 3;              // 0..383
  const int bhl = rest & 3;
  const int j = rest >> 2;              // 0..95
  const int bh = xcd * 4 + bhl;
  int ti, t0, t1, split, c;
  if (j < 32){ ti = 32 + j; t0 = 0; t1 = 32; split = 1; c = 0; }
  else {
    int k = j - 32; int v = 32 - (k >> 1);      // v: 32..1
    if ((k & 1) == 0){ ti = v - 1;  t0 = 0;  t1 = ti + 1; split = 0; c = 0; }
    else             { ti = 31 + v; t0 = 32; t1 = ti + 1; split = 1; c = 1; }
  }
  const int nt = ti + 1;
  const int wq0 = ti * 32 + w * 16;
  const int b_out = bh >> 4, h_out = bh & 15;

  const int kg = (ln & 7) ^ (ln >> 3);
  const int vg = (ln & 3) ^ ((ln >> 3) & 3);
  const u16* kp0 = kb + ((size_t)bh*2048 + (ln >> 3))*64 + kg*8;
  const u16* vp0 = vt + ((size_t)bh*64  + (ln >> 2))*2048 + vg*8;

  #define STAGE(bf_, kv0_) do { \
    gll16(&Ks[bf_][(w*2 + 0)*512], kp0 + (size_t)((kv0_) + (w*2+0)*8)*64); \
    gll16(&Ks[bf_][(w*2 + 1)*512], kp0 + (size_t)((kv0_) + (w*2+1)*8)*64); \
    gll16(&Vs[bf_][(w*2 + 0)*512], vp0 + (size_t)((w*2+0)*16)*2048 + (kv0_)); \
    gll16(&Vs[bf_][(w*2 + 1)*512], vp0 + (size_t)((w*2+1)*16)*2048 + (kv0_)); \
  } while(0)

  bf16x8 qf[2];
  #pragma unroll
  for (int ks = 0; ks < 2; ks++)
    qf[ks] = *(const bf16x8*)(qb + ((size_t)bh*2048 + wq0 + l15)*64 + ks*32 + lg*8);

  f32x4 ot[4] = {};
  float m_run = -3e38f;
  float l_loc = 0.f;

  // compute one kv tile from static buffer BUF (addresses loop-invariant)
  #define BODY(BUF) do { \
    const int kv0 = t * 32; \
    f32x4 st[2] = {}; \
    __builtin_amdgcn_s_setprio(1); \
    _Pragma("unroll") \
    for (int ks = 0; ks < 2; ks++){ \
      bf16x8 kf[2]; \
      _Pragma("unroll") \
      for (int an = 0; an < 2; an++) \
        kf[an] = *(const bf16x8*)(&Ks[BUF][(an*16 + l15)*64 + (((ks*4 + lg) ^ (l15 & 7)) * 8)]); \
      _Pragma("unroll") \
      for (int an = 0; an < 2; an++) \
        st[an] = __builtin_amdgcn_mfma_f32_16x16x32_bf16(kf[an], qf[ks], st[an], 0, 0, 0); \
    } \
    __builtin_amdgcn_s_setprio(0); \
    if (t == nt - 1){ \
      _Pragma("unroll") \
      for (int an = 0; an < 2; an++) \
        _Pragma("unroll") \
        for (int rr = 0; rr < 4; rr++){ \
          int kv = kv0 + an*16 + lg*4 + rr; \
          int q  = wq0 + l15; \
          if (kv > q) st[an][rr] = -3e38f; \
        } \
    } \
    float mx0 = fmaxf(fmaxf(st[0][0], st[0][1]), fmaxf(st[0][2], st[0][3])); \
    float mx1 = fmaxf(fmaxf(st[1][0], st[1][1]), fmaxf(st[1][2], st[1][3])); \
    float lmax = fmaxf(mx0, mx1); \
    float m0 = m_run; \
    if (__any(lmax > m0 + 8.f)){ \
      float tmax = fmaxf(lmax, __shfl_xor(lmax, 16)); \
      tmax = fmaxf(tmax, __shfl_xor(tmax, 32)); \
      float mnew = fmaxf(m0, tmax); \
      float alpha = __builtin_amdgcn_exp2f((m0 - mnew) * L2E); \
      m_run = mnew; \
      l_loc *= alpha; \
      _Pragma("unroll") \
      for (int dm = 0; dm < 4; dm++){ \
        ot[dm][0] *= alpha; ot[dm][1] *= alpha; \
        ot[dm][2] *= alpha; ot[dm][3] *= alpha; \
      } \
      m0 = mnew; \
    } \
    u32 pk01[2], pk23[2]; \
    float psum[2]; \
    _Pragma("unroll") \
    for (int an = 0; an < 2; an++){ \
      float e0 = __builtin_amdgcn_exp2f((st[an][0] - m0) * L2E); \
      float e1 = __builtin_amdgcn_exp2f((st[an][1] - m0) * L2E); \
      float e2 = __builtin_amdgcn_exp2f((st[an][2] - m0) * L2E); \
      float e3 = __builtin_amdgcn_exp2f((st[an][3] - m0) * L2E); \
      psum[an] = (e0 + e1) + (e2 + e3); \
      pk01[an] = pack2bf(e0, e1); \
      pk23[an] = pack2bf(e2, e3); \
    } \
    l_loc += psum[0] + psum[1]; \
    const int s0l = l15 | ((lg & 1) << 5); \
    const int s2l = s0l | 16; \
    const bool hi = (lg >> 1) & 1; \
    bf16x8 vfr[4]; \
    _Pragma("unroll") \
    for (int dm = 0; dm < 4; dm++) \
      vfr[dm] = *(const bf16x8*)(&Vs[BUF][(dm*16 + l15)*32 + ((lg ^ ((l15 >> 1) & 3)) * 8)]); \
    u32 a0 = __shfl(pk01[0], s0l), b0 = __shfl(pk01[1], s0l); \
    u32 a1 = __shfl(pk23[0], s0l), b1 = __shfl(pk23[1], s0l); \
    u32 a2 = __shfl(pk01[0], s2l), b2 = __shfl(pk01[1], s2l); \
    u32 a3 = __shfl(pk23[0], s2l), b3 = __shfl(pk23[1], s2l); \
    union { u32 u[4]; bf16x8 v; } pf; \
    pf.u[0] = hi ? b0 : a0; \
    pf.u[1] = hi ? b1 : a1; \
    pf.u[2] = hi ? b2 : a2; \
    pf.u[3] = hi ? b3 : a3; \
    __builtin_amdgcn_s_setprio(1); \
    _Pragma("unroll") \
    for (int dm = 0; dm < 4; dm++) \
      ot[dm] = __builtin_amdgcn_mfma_f32_16x16x32_bf16(vfr[dm], pf.v, ot[dm], 0, 0, 0); \
    __builtin_amdgcn_s_setprio(0); \
  } while(0)

  STAGE(0, t0 * 32);
  int t = t0;
  #pragma unroll 1
  while (t < t1){
    // ---- half A: compute buf0 (tile t), stage t+1 into buf1 ----
    if (t + 1 < t1){
      STAGE(1, (t + 1) * 32);
      asm volatile("s_waitcnt vmcnt(4)" ::: "memory");
    } else {
      asm volatile("s_waitcnt vmcnt(0)" ::: "memory");
    }
    __builtin_amdgcn_s_barrier();
    __builtin_amdgcn_sched_barrier(0);
    BODY(0);
    __builtin_amdgcn_s_barrier();
    t++;
    if (t >= t1) break;
    // ---- half B: compute buf1 (tile t), stage t+1 into buf0 ----
    if (t + 1 < t1){
      STAGE(0, (t + 1) * 32);
      asm volatile("s_waitcnt vmcnt(4)" ::: "memory");
    } else {
      asm volatile("s_waitcnt vmcnt(0)" ::: "memory");
    }
    __builtin_amdgcn_s_barrier();
    __builtin_amdgcn_sched_barrier(0);
    BODY(1);
    __builtin_amdgcn_s_barrier();
    t++;
  }
  #undef STAGE
  #undef BODY

  float lsum = l_loc + __shfl_xor(l_loc, 16);
  lsum += __shfl_xor(lsum, 32);
  if (!split){
    float inv = 1.0f / lsum;
    int q = wq0 + l15;
    u16* obase = ob + (((size_t)b_out*2048 + q)*16 + h_out)*64 + lg*4;
    #pragma unroll
    for (int dm = 0; dm < 4; dm++){
      ushort4 pk;
      pk.x = f2bf(ot[dm][0] * inv);
      pk.y = f2bf(ot[dm][1] * inv);
      pk.z = f2bf(ot[dm][2] * inv);
      pk.w = f2bf(ot[dm][3] * inv);
      *(ushort4*)(obase + dm*16) = pk;
    }
  } else {
    const int sidx = (bh*32 + (ti - 32))*2 + c;
    const int qloc = w*16 + l15;
    u16* pbase = pO + (size_t)sidx*2048 + qloc*64 + lg*4;
    #pragma unroll
    for (int dm = 0; dm < 4; dm++){
      ushort4 pk;
      pk.x = f2bf(ot[dm][0]);
      pk.y = f2bf(ot[dm][1]);
      pk.z = f2bf(ot[dm][2]);
      pk.w = f2bf(ot[dm][3]);
      *(ushort4*)(pbase + dm*16) = pk;
    }
    if (lg == 0){
      pS[sidx*64 + qloc*2 + 0] = m_run;
      pS[sidx*64 + qloc*2 + 1] = lsum;
    }
  }
}

// ---------------- combine the two kv-chunks of tiles 32..63 ----------------
__global__ __launch_bounds__(128) void attn_combine(
    const u16* __restrict__ pO, const float* __restrict__ pS,
    u16* __restrict__ ob)
{
  const float L2E = 1.4426950408889634f;
  const int p = blockIdx.x;             // 0..1023
  const int bh = p >> 5;
  const int ti = 32 + (p & 31);
  const int s0 = (bh*32 + (ti - 32))*2;
  const int tid = threadIdx.x;
  const int row = tid >> 2, seg = tid & 3;

  float m0 = pS[s0*64 + row*2],     l0 = pS[s0*64 + row*2 + 1];
  float m1 = pS[(s0+1)*64 + row*2], l1 = pS[(s0+1)*64 + row*2 + 1];
  float m = fmaxf(m0, m1);
  float f0 = __builtin_amdgcn_exp2f((m0 - m) * L2E);
  float f1 = __builtin_amdgcn_exp2f((m1 - m) * L2E);
  float inv = 1.0f / (l0*f0 + l1*f1);
  f0 *= inv; f1 *= inv;

  union { int4 v[2]; u16 u[16]; } o0, o1, od;
  const u16* p0 = pO + (size_t)s0*2048 + row*64 + seg*16;
  const u16* p1 = pO + (size_t)(s0+1)*2048 + row*64 + seg*16;
  o0.v[0] = ((const int4*)p0)[0]; o0.v[1] = ((const int4*)p0)[1];
  o1.v[0] = ((const int4*)p1)[0]; o1.v[1] = ((const int4*)p1)[1];
  #pragma unroll
  for (int i = 0; i < 16; i++)
    od.u[i] = f2bf(bf2f(o0.u[i])*f0 + bf2f(o1.u[i])*f1);

  const int b = bh >> 4, h = bh & 15;
  const int q = ti*32 + row;
  u16* dst = ob + (((size_t)b*2048 + q)*16 + h)*64 + seg*16;
  ((int4*)dst)[0] = od.v[0];
  ((int4*)dst)[1] = od.v[1];
}

extern "C" void kernel_launch(void* const* d_in, const int* in_sizes, int n_in,
                              void* d_out, int out_size, void* d_ws, size_t ws_size,
                              hipStream_t stream)
{
  (void)in_sizes; (void)n_in; (void)out_size; (void)ws_size;
  const float* x    = (const float*)d_in[0];
  const float* wqkv = (const float*)d_in[2];
  const float* wo   = (const float*)d_in[3];
  float* out = (float*)d_out;

  char* ws = (char*)d_ws;
  u16* xb    = (u16*)(ws);
  u16* wqkvb = (u16*)(ws + ((size_t)8  << 20));
  u16* wob   = (u16*)(ws + ((size_t)14 << 20));
  u16* qbuf  = (u16*)(ws + ((size_t)16 << 20));
  u16* kbuf  = (u16*)(ws + ((size_t)24 << 20));
  u16* vtbuf = (u16*)(ws + ((size_t)40 << 20));
  u16* obuf  = (u16*)(ws + ((size_t)48 << 20));
  // partial buffers reuse xb/wqkvb (dead after gemm1 completes, stream-ordered)
  u16*   pO = xb;                         // 2048 slots x 4KB = 8MB
  float* pS = (float*)wqkvb;              // 2048 x 256B = 512KB

  cast3_f32_bf16<<<2048, 256, 0, stream>>>(x, wqkv, wo, xb, wqkvb, wob);
  // gemm1 writes V directly transposed into vtbuf (no separate transpose kernel)
  gemm_dbuf<128,128,3><<<dim3(24, 32), 256, 0, stream>>>(xb, wqkvb, qbuf, kbuf, vtbuf, nullptr, 0);
  attn_fwd<<<3072, 128, 0, stream>>>(qbuf, kbuf, vtbuf, obuf, pO, pS);
  attn_combine<<<1024, 128, 0, stream>>>(pO, pS, obuf);
  gemm_dbuf<64,128,6><<<dim3(8, 64), 256, 0, stream>>>(obuf, wob, nullptr, nullptr, nullptr, out, 1);
}